// Round 8
// baseline (431.190 us; speedup 1.0000x reference)
//
#include <hip/hip_runtime.h>
#include <hip/hip_bf16.h>

// VQ codebook lookup via split-bf16 MFMA + margin-based candidate recheck.
// x[16,256,32,32] f32, E[256,8192] f32, N=16384 tokens, K=8192 codes.
// R8: S = (xh+xl).eh via 2 bf16 MFMAs (error = x.el, std ~2.3e-3; MARGIN
// 0.035 = ~11 sigma of the error difference). dist = c_k - 2S. Tokens with
// global top-2 gap < MARGIN: exact fp32 recheck of candidate codes; rare
// "hard" tokens get a full-K exact scan. Exact path = ascending-d fmaf chain
// (validated vs numpy R1-R7). Staging: conflict-free XOR-swizzled
// global_load_lds (R6/R7-verified). LDS 35 KB -> 4 blocks/CU.

#define D_   256
#define HW_  1024
#define N_   16384
#define K_   8192
#define NB_  32              // 32 code-blocks of 256
#define MARGIN 0.035f        // ~11 sigma of approx-error difference (see header)

#define OUT1_OFF 4194304     // B*D*H*W
#define IND_OFF  8388608

typedef __attribute__((ext_vector_type(8))) short bf16x8;   // 8 bf16 = 4 VGPR
typedef __attribute__((ext_vector_type(4))) float f32x4;

__device__ __forceinline__ unsigned long long pack_dk(float dist, int k) {
    unsigned db = __float_as_uint(dist);
    unsigned mono = (db & 0x80000000u) ? ~db : (db | 0x80000000u);
    return ((unsigned long long)mono << 32) | (unsigned)k;
}

// async global->LDS DMA: lane i of the wave lands at ldsbase + 16*i.
__device__ __forceinline__ void async_copy16(const void* g, void* l) {
    __builtin_amdgcn_global_load_lds(
        (const __attribute__((address_space(1))) void*)g,
        (__attribute__((address_space(3))) void*)l, 16, 0, 0);
}

// ---------------- codebook column norms + counter zeroing -------------------
__global__ __launch_bounds__(256)
void cnorm_kernel(const float* __restrict__ E, float* __restrict__ c,
                  int* __restrict__ counters) {
    if (blockIdx.x == 0 && threadIdx.x < 2) counters[threadIdx.x] = 0;
    __shared__ float part[8][32];
    const int tid = threadIdx.x;
    const int cl = tid & 31, q = tid >> 5;
    const int k = blockIdx.x * 32 + cl;
    float s = 0.f;
    #pragma unroll 8
    for (int d = q * 32; d < q * 32 + 32; ++d) {
        float v = E[(size_t)d * K_ + k];
        s = fmaf(v, v, s);
    }
    part[q][cl] = s;
    __syncthreads();
    if (tid < 32) {   // fixed combine order: deterministic
        float t0 = (part[0][tid] + part[1][tid]) + (part[2][tid] + part[3][tid]);
        float t1 = (part[4][tid] + part[5][tid]) + (part[6][tid] + part[7][tid]);
        c[blockIdx.x * 32 + tid] = t0 + t1;
    }
}

// ---------------- prep: split x fp32 -> (hi,lo) bf16 planes, transposed -----
__global__ __launch_bounds__(256)
void prep_x(const float* __restrict__ x, ushort* __restrict__ xh, ushort* __restrict__ xl) {
    __shared__ float t[32][33];
    const int s0 = blockIdx.x * 32, d0 = blockIdx.y * 32, b = blockIdx.z;
    const int tid = threadIdx.x;
    #pragma unroll
    for (int j = 0; j < 4; ++j) {
        int i = tid + 256 * j; int dd = i >> 5, ss = i & 31;
        t[dd][ss] = x[(size_t)b * 262144 + (size_t)(d0 + dd) * 1024 + s0 + ss];
    }
    __syncthreads();
    #pragma unroll
    for (int j = 0; j < 4; ++j) {
        int i = tid + 256 * j; int ss = i >> 5, dd = i & 31;
        float v = t[dd][ss];
        __hip_bfloat16 h = __float2bfloat16(v);
        float r = v - __bfloat162float(h);
        __hip_bfloat16 l = __float2bfloat16(r);
        size_t o = (size_t)(b * 1024 + s0 + ss) * D_ + d0 + dd;
        xh[o] = *(ushort*)&h;
        xl[o] = *(ushort*)&l;
    }
}

// E[d][k] -> eh[k][d] (hi plane only — el dropped in R8)
__global__ __launch_bounds__(256)
void prep_e(const float* __restrict__ E, ushort* __restrict__ eh) {
    __shared__ float t[32][33];
    const int k0 = blockIdx.x * 32, d0 = blockIdx.y * 32;
    const int tid = threadIdx.x;
    #pragma unroll
    for (int j = 0; j < 4; ++j) {
        int i = tid + 256 * j; int dd = i >> 5, kk = i & 31;
        t[dd][kk] = E[(size_t)(d0 + dd) * K_ + k0 + kk];
    }
    __syncthreads();
    #pragma unroll
    for (int j = 0; j < 4; ++j) {
        int i = tid + 256 * j; int kk = i >> 5, dd = i & 31;
        __hip_bfloat16 h = __float2bfloat16(t[dd][kk]);
        eh[(size_t)(k0 + kk) * D_ + d0 + dd] = *(ushort*)&h;
    }
}

// ---------------- MFMA distance + per-token top-2 per 256-code block --------
// grid (NB_=32, 128), block 256 = 4 waves (2x2), wave tile 64 tokens x 128 codes.
// LDS: row-major 64B rows of 4x16B chunks, chunk position = chunk ^ ((row>>1)&3)
// (DMA writes lane-contiguous, frag reads 2/bank — conflict-free, R6-verified).
__global__ __launch_bounds__(256, 2)
void mfma_kernel(const ushort* __restrict__ xh, const ushort* __restrict__ xl,
                 const ushort* __restrict__ eh,
                 const float* __restrict__ c,
                 float* __restrict__ pd1, int* __restrict__ pi1, float* __restrict__ pd2) {
    __shared__ __align__(16) ushort Ah[128 * 32], Al[128 * 32];   // 8 KB each
    __shared__ __align__(16) ushort Bh[256 * 32];                 // 16 KB
    __shared__ float redm1[128][2], redm2[128][2];
    __shared__ int   redi1[128][2];

    const int tid = threadIdx.x;
    const int nb = blockIdx.x, mb = blockIdx.y;
    const int n0 = mb * 128, k0 = nb * 256;
    const int lane = tid & 63, w = tid >> 6;
    const int wy = w >> 1, wx = w & 1;
    const int l15 = lane & 15, lq = lane >> 4;

    // staging descriptors: slot = row*4 + pos, source chunk = pos ^ ((row>>1)&3).
    size_t aoff[2]; ushort* adst_h[2]; ushort* adst_l[2];
    #pragma unroll
    for (int g = 0; g < 2; ++g) {
        int slot = (w * 2 + g) * 64 + lane;
        int t = slot >> 2, cp = slot & 3;
        int cs = cp ^ ((t >> 1) & 3);
        aoff[g] = (size_t)(n0 + t) * D_ + cs * 8;
        adst_h[g] = Ah + (w * 2 + g) * 512;
        adst_l[g] = Al + (w * 2 + g) * 512;
    }
    size_t boff[4]; ushort* bdst[4];
    #pragma unroll
    for (int g = 0; g < 4; ++g) {
        int slot = (w * 4 + g) * 64 + lane;
        int t = slot >> 2, cp = slot & 3;
        int cs = cp ^ ((t >> 1) & 3);
        boff[g] = (size_t)(k0 + t) * D_ + cs * 8;
        bdst[g] = Bh + (w * 4 + g) * 512;
    }
    // fragment read offsets (ushort units), fixed across iterations
    int aro[4], bro[8];
    #pragma unroll
    for (int mt = 0; mt < 4; ++mt) {
        int R = wy * 64 + mt * 16 + l15;
        aro[mt] = R * 32 + ((lq ^ ((R >> 1) & 3)) * 8);
    }
    #pragma unroll
    for (int nt = 0; nt < 8; ++nt) {
        int R = wx * 128 + nt * 16 + l15;
        bro[nt] = R * 32 + ((lq ^ ((R >> 1) & 3)) * 8);
    }

    f32x4 acc[4][8];
    #pragma unroll
    for (int mt = 0; mt < 4; ++mt)
        #pragma unroll
        for (int nt = 0; nt < 8; ++nt) acc[mt][nt] = (f32x4){0.f, 0.f, 0.f, 0.f};

    for (int db = 0; db < 8; ++db) {
        const int d0 = db * 32;
        __syncthreads();   // prior readers done before DMA lands
        #pragma unroll
        for (int g = 0; g < 2; ++g) {
            async_copy16(xh + aoff[g] + d0, adst_h[g]);
            async_copy16(xl + aoff[g] + d0, adst_l[g]);
        }
        #pragma unroll
        for (int g = 0; g < 4; ++g)
            async_copy16(eh + boff[g] + d0, bdst[g]);
        __syncthreads();   // drains vmcnt (DMA complete)

        bf16x8 a_h[4], a_l[4];
        #pragma unroll
        for (int mt = 0; mt < 4; ++mt) {
            a_h[mt] = *(const bf16x8*)&Ah[aro[mt]];
            a_l[mt] = *(const bf16x8*)&Al[aro[mt]];
        }
        #pragma unroll
        for (int nt = 0; nt < 8; ++nt) {
            bf16x8 b_h = *(const bf16x8*)&Bh[bro[nt]];
            #pragma unroll
            for (int mt = 0; mt < 4; ++mt) {
                acc[mt][nt] = __builtin_amdgcn_mfma_f32_16x16x32_bf16(a_h[mt], b_h, acc[mt][nt], 0, 0, 0);
                acc[mt][nt] = __builtin_amdgcn_mfma_f32_16x16x32_bf16(a_l[mt], b_h, acc[mt][nt], 0, 0, 0);
            }
        }
    }

    float cv[8];
    #pragma unroll
    for (int nt = 0; nt < 8; ++nt) cv[nt] = c[k0 + wx * 128 + nt * 16 + l15];

    float m1[16], m2[16]; int i1[16];
    #pragma unroll
    for (int mt = 0; mt < 4; ++mt)
        #pragma unroll
        for (int r = 0; r < 4; ++r) {
            int p = mt * 4 + r;
            float a = 3.4e38f, b2 = 3.4e38f; int ai = -1;
            #pragma unroll
            for (int nt = 0; nt < 8; ++nt) {
                float d = fmaf(-2.f, acc[mt][nt][r], cv[nt]);
                int k = k0 + wx * 128 + nt * 16 + l15;
                if (d < a) { b2 = a; a = d; ai = k; } else if (d < b2) b2 = d;
            }
            m1[p] = a; i1[p] = ai; m2[p] = b2;
        }
    #pragma unroll
    for (int s = 1; s < 16; s <<= 1) {
        #pragma unroll
        for (int p = 0; p < 16; ++p) {
            float n1 = __shfl_xor(m1[p], s);
            int   ni = __shfl_xor(i1[p], s);
            float n2 = __shfl_xor(m2[p], s);
            if (n1 < m1[p]) { m2[p] = fminf(m1[p], n2); m1[p] = n1; i1[p] = ni; }
            else            { m2[p] = fminf(m2[p], n1); }
        }
    }
    if (l15 == 0) {
        #pragma unroll
        for (int mt = 0; mt < 4; ++mt)
            #pragma unroll
            for (int r = 0; r < 4; ++r) {
                int p = mt * 4 + r;
                int t = wy * 64 + mt * 16 + lq * 4 + r;
                redm1[t][wx] = m1[p]; redi1[t][wx] = i1[p]; redm2[t][wx] = m2[p];
            }
    }
    __syncthreads();
    if (tid < 128) {
        float a = redm1[tid][0], b2 = redm2[tid][0]; int ai = redi1[tid][0];
        float n1 = redm1[tid][1], n2 = redm2[tid][1]; int ni = redi1[tid][1];
        if (n1 < a) { b2 = fminf(a, n2); a = n1; ai = ni; }
        else        { b2 = fminf(b2, n1); }
        size_t o = (size_t)nb * N_ + n0 + tid;
        pd1[o] = a; pi1[o] = ai; pd2[o] = b2;
    }
}

// ---------------- merge 32 blocks; flag via sign bit; enumerate candidates --
// counters[0]=pairs, [1]=hard
__global__ __launch_bounds__(256)
void merge_flag(const float* __restrict__ pd1, const int* __restrict__ pi1,
                const float* __restrict__ pd2,
                int* __restrict__ idx, int* __restrict__ counters,
                unsigned long long* __restrict__ key,
                unsigned int* __restrict__ pairs, int* __restrict__ hard) {
    int n = blockIdx.x * 256 + threadIdx.x;
    float a = 3.4e38f, b2 = 3.4e38f; int ai = -1;
    for (int nb = 0; nb < NB_; ++nb) {
        float n1 = pd1[(size_t)nb * N_ + n];
        int   ni = pi1[(size_t)nb * N_ + n];
        float n2 = pd2[(size_t)nb * N_ + n];
        if (n1 < a) { b2 = fminf(a, n2); a = n1; ai = ni; }
        else        { b2 = fminf(b2, n1); }
    }
    if (b2 - a < MARGIN) {
        const float W = a + MARGIN;
        key[n] = ~0ULL;
        idx[n] = 0x80000000 | ai;          // flagged: resolve from key later
        bool hardtok = false;
        for (int nb = 0; nb < NB_; ++nb)
            if (pd2[(size_t)nb * N_ + n] <= W) hardtok = true;
        if (hardtok) {
            int q = atomicAdd(&counters[1], 1); hard[q] = n;
        } else {
            for (int nb = 0; nb < NB_; ++nb)
                if (pd1[(size_t)nb * N_ + n] <= W) {
                    int q = atomicAdd(&counters[0], 1);
                    pairs[q] = ((unsigned)n << 13) | (unsigned)pi1[(size_t)nb * N_ + n];
                }
        }
    } else {
        idx[n] = ai;
    }
}

// ---------------- fused exact fp32 recheck (pairs + hard) -------------------
// blocks [0,128): 4 threads per (token, candidate); blocks [128,384): full-K
// scan tasks for hard tokens (8 x 1024-code chunks each, coalesced E rows).
__global__ __launch_bounds__(256)
void recheck(const float* __restrict__ x, const float* __restrict__ E,
             const float* __restrict__ c, const unsigned int* __restrict__ pairs,
             const int* __restrict__ hard, const int* __restrict__ counters,
             unsigned long long* __restrict__ key) {
    if (blockIdx.x < 128) {
        int items = counters[0] * 4;
        for (int it = blockIdx.x * 256 + threadIdx.x; it < items; it += 128 * 256) {
            int p = it >> 2, q = it & 3;   // quads stay intact: stride % 4 == 0
            unsigned v = pairs[p];
            int n = v >> 13, k = v & 8191;
            int b = n >> 10, s = n & 1023;
            const float* xb = x + (size_t)b * 262144 + s;
            const float* eb = E + k;
            float acc = 0.f;
            const int d0 = q * 64;
            #pragma unroll 8
            for (int d = d0; d < d0 + 64; ++d)
                acc = fmaf(xb[(size_t)d * HW_], eb[(size_t)d * K_], acc);
            float o1 = __shfl_xor(acc, 1); float s2 = acc + o1;
            float o2 = __shfl_xor(s2, 2);  float tot = s2 + o2;   // ((q0+q1)+(q2+q3))
            if (q == 0) atomicMin(key + n, pack_dk(fmaf(-2.f, tot, c[k]), k));
        }
    } else {
        int tasks = counters[1] * 8;
        for (int t = blockIdx.x - 128; t < tasks; t += 256) {
            int n = hard[t >> 3];
            int k = (t & 7) * 1024 + threadIdx.x * 4;
            int b = n >> 10, s = n & 1023;
            const float* xb = x + (size_t)b * 262144 + s;
            float a0 = 0.f, a1 = 0.f, a2 = 0.f, a3 = 0.f;
            for (int d = 0; d < D_; ++d) {
                float xv = xb[(size_t)d * HW_];
                const float* er = E + (size_t)d * K_ + k;
                a0 = fmaf(xv, er[0], a0);
                a1 = fmaf(xv, er[1], a1);
                a2 = fmaf(xv, er[2], a2);
                a3 = fmaf(xv, er[3], a3);
            }
            float d0 = fmaf(-2.f, a0, c[k]);
            float d1 = fmaf(-2.f, a1, c[k + 1]);
            float d2 = fmaf(-2.f, a2, c[k + 2]);
            float d3 = fmaf(-2.f, a3, c[k + 3]);
            float bd = d0; int bi = k;                     // ascending k, strict <
            if (d1 < bd) { bd = d1; bi = k + 1; }
            if (d2 < bd) { bd = d2; bi = k + 2; }
            if (d3 < bd) { bd = d3; bi = k + 3; }
            atomicMin(key + n, pack_dk(bd, bi));
        }
    }
}

// ---------------- gather + write outputs (fixup fused via sign bit) ---------
__global__ __launch_bounds__(256)
void write_kernel(const float* __restrict__ x, const float* __restrict__ E,
                  const int* __restrict__ idx, const unsigned long long* __restrict__ key,
                  float* __restrict__ out) {
    __shared__ int kst[64];
    const int n0 = blockIdx.x * 64;
    const int b = n0 >> 10, s0 = n0 & 1023;
    const int tid = threadIdx.x;
    if (tid < 64) {
        int v = idx[n0 + tid];
        int k = (v < 0) ? (int)(key[n0 + tid] & 8191ULL) : v;
        kst[tid] = k;
        out[IND_OFF + n0 + tid] = (float)k;
    }
    __syncthreads();
    const int lane = tid & 63, dq = tid >> 6;
    const int kk = kst[lane];
    const float* xb = x + (size_t)b * D_ * HW_ + s0 + lane;
    float* o0 = out + (size_t)b * D_ * HW_ + s0 + lane;
    float* o1 = o0 + OUT1_OFF;
    for (int d = dq; d < D_; d += 4) {
        float q  = E[(size_t)d * K_ + kk];
        float xv = xb[(size_t)d * HW_];
        float qmx = q - xv;
        o0[(size_t)d * HW_] = xv + qmx;
        o1[(size_t)d * HW_] = q;
    }
}

extern "C" void kernel_launch(void* const* d_in, const int* in_sizes, int n_in,
                              void* d_out, int out_size, void* d_ws, size_t ws_size,
                              hipStream_t stream) {
    const float* x = (const float*)d_in[0];
    const float* E = (const float*)d_in[1];
    float* out = (float*)d_out;

    char* p = (char*)d_ws;
    ushort* xh = (ushort*)p;                 p += (size_t)N_ * D_ * 2;   // 8 MB
    ushort* xl = (ushort*)p;                 p += (size_t)N_ * D_ * 2;   // 8 MB
    ushort* eh = (ushort*)p;                 p += (size_t)K_ * D_ * 2;   // 4 MB
    float*  c  = (float*)p;                  p += (size_t)K_ * 4;
    float*  pd1 = (float*)p;                 p += (size_t)NB_ * N_ * 4;  // 2 MB
    int*    pi1 = (int*)p;                   p += (size_t)NB_ * N_ * 4;
    float*  pd2 = (float*)p;                 p += (size_t)NB_ * N_ * 4;
    int*    idx = (int*)p;                   p += (size_t)N_ * 4;
    unsigned long long* key = (unsigned long long*)p; p += (size_t)N_ * 8;
    unsigned int* pairs = (unsigned int*)p;  p += (size_t)524288 * 4;    // 2 MB cap
    int*    hard = (int*)p;                  p += (size_t)N_ * 4;
    int*    counters = (int*)p;              p += 256;

    cnorm_kernel<<<K_ / 32, 256, 0, stream>>>(E, c, counters);
    prep_x<<<dim3(32, 8, 16), 256, 0, stream>>>(x, xh, xl);
    prep_e<<<dim3(256, 8), 256, 0, stream>>>(E, eh);
    mfma_kernel<<<dim3(NB_, 128), 256, 0, stream>>>(xh, xl, eh, c, pd1, pi1, pd2);
    merge_flag<<<N_ / 256, 256, 0, stream>>>(pd1, pi1, pd2, idx, counters, key, pairs, hard);
    recheck<<<384, 256, 0, stream>>>(x, E, c, pairs, hard, counters, key);
    write_kernel<<<N_ / 64, 256, 0, stream>>>(x, E, idx, key, out);
}

// Round 9
// 369.766 us; speedup vs baseline: 1.1661x; 1.1661x over previous
//
#include <hip/hip_runtime.h>
#include <hip/hip_bf16.h>

// VQ codebook lookup via split-bf16 MFMA + margin-based candidate recheck.
// x[16,256,32,32] f32, E[256,8192] f32, N=16384 tokens, K=8192 codes.
// S = (xh+xl).eh via 2 bf16 MFMAs; dist = c_k - 2S; dist error std ~1.1e-3.
// MARGIN 0.02 ~ 13 sigma of pairwise error difference. Flagged tokens:
// block top-1s in window -> exact pair recheck; blocks with top-2 in window
// -> exact 256-code BLOCK scan (covers any rank in that block; R9 change —
// replaces the full-K scan whose 8MB/token reads blew up the R8 tail).
// Exact path = ascending-d fmaf chain (validated vs numpy R1-R8).
// Staging: conflict-free XOR-swizzled global_load_lds (R6/R7-verified).

#define D_   256
#define HW_  1024
#define N_   16384
#define K_   8192
#define NB_  32              // 32 code-blocks of 256
#define MARGIN 0.02f         // ~13 sigma of approx-error difference

#define OUT1_OFF 4194304     // B*D*H*W
#define IND_OFF  8388608

typedef __attribute__((ext_vector_type(8))) short bf16x8;   // 8 bf16 = 4 VGPR
typedef __attribute__((ext_vector_type(4))) float f32x4;

__device__ __forceinline__ unsigned long long pack_dk(float dist, int k) {
    unsigned db = __float_as_uint(dist);
    unsigned mono = (db & 0x80000000u) ? ~db : (db | 0x80000000u);
    return ((unsigned long long)mono << 32) | (unsigned)k;
}

// async global->LDS DMA: lane i of the wave lands at ldsbase + 16*i.
__device__ __forceinline__ void async_copy16(const void* g, void* l) {
    __builtin_amdgcn_global_load_lds(
        (const __attribute__((address_space(1))) void*)g,
        (__attribute__((address_space(3))) void*)l, 16, 0, 0);
}

// ---------------- codebook column norms + counter zeroing -------------------
__global__ __launch_bounds__(256)
void cnorm_kernel(const float* __restrict__ E, float* __restrict__ c,
                  int* __restrict__ counters) {
    if (blockIdx.x == 0 && threadIdx.x < 2) counters[threadIdx.x] = 0;
    __shared__ float part[8][32];
    const int tid = threadIdx.x;
    const int cl = tid & 31, q = tid >> 5;
    const int k = blockIdx.x * 32 + cl;
    float s = 0.f;
    #pragma unroll 8
    for (int d = q * 32; d < q * 32 + 32; ++d) {
        float v = E[(size_t)d * K_ + k];
        s = fmaf(v, v, s);
    }
    part[q][cl] = s;
    __syncthreads();
    if (tid < 32) {   // fixed combine order: deterministic
        float t0 = (part[0][tid] + part[1][tid]) + (part[2][tid] + part[3][tid]);
        float t1 = (part[4][tid] + part[5][tid]) + (part[6][tid] + part[7][tid]);
        c[blockIdx.x * 32 + tid] = t0 + t1;
    }
}

// ---------------- prep: split x fp32 -> (hi,lo) bf16 planes, transposed -----
__global__ __launch_bounds__(256)
void prep_x(const float* __restrict__ x, ushort* __restrict__ xh, ushort* __restrict__ xl) {
    __shared__ float t[32][33];
    const int s0 = blockIdx.x * 32, d0 = blockIdx.y * 32, b = blockIdx.z;
    const int tid = threadIdx.x;
    #pragma unroll
    for (int j = 0; j < 4; ++j) {
        int i = tid + 256 * j; int dd = i >> 5, ss = i & 31;
        t[dd][ss] = x[(size_t)b * 262144 + (size_t)(d0 + dd) * 1024 + s0 + ss];
    }
    __syncthreads();
    #pragma unroll
    for (int j = 0; j < 4; ++j) {
        int i = tid + 256 * j; int ss = i >> 5, dd = i & 31;
        float v = t[dd][ss];
        __hip_bfloat16 h = __float2bfloat16(v);
        float r = v - __bfloat162float(h);
        __hip_bfloat16 l = __float2bfloat16(r);
        size_t o = (size_t)(b * 1024 + s0 + ss) * D_ + d0 + dd;
        xh[o] = *(ushort*)&h;
        xl[o] = *(ushort*)&l;
    }
}

// E[d][k] -> eh[k][d] (hi plane only)
__global__ __launch_bounds__(256)
void prep_e(const float* __restrict__ E, ushort* __restrict__ eh) {
    __shared__ float t[32][33];
    const int k0 = blockIdx.x * 32, d0 = blockIdx.y * 32;
    const int tid = threadIdx.x;
    #pragma unroll
    for (int j = 0; j < 4; ++j) {
        int i = tid + 256 * j; int dd = i >> 5, kk = i & 31;
        t[dd][kk] = E[(size_t)(d0 + dd) * K_ + k0 + kk];
    }
    __syncthreads();
    #pragma unroll
    for (int j = 0; j < 4; ++j) {
        int i = tid + 256 * j; int kk = i >> 5, dd = i & 31;
        __hip_bfloat16 h = __float2bfloat16(t[dd][kk]);
        eh[(size_t)(k0 + kk) * D_ + d0 + dd] = *(ushort*)&h;
    }
}

// ---------------- MFMA distance + per-token top-2 per 256-code block --------
// grid (NB_=32, 128), block 256 = 4 waves (2x2), wave tile 64 tokens x 128 codes.
// UNCHANGED from R8 (verified; ~194 us). LDS: 64B rows of 4x16B chunks,
// chunk position = chunk ^ ((row>>1)&3) — conflict-free both directions.
__global__ __launch_bounds__(256, 2)
void mfma_kernel(const ushort* __restrict__ xh, const ushort* __restrict__ xl,
                 const ushort* __restrict__ eh,
                 const float* __restrict__ c,
                 float* __restrict__ pd1, int* __restrict__ pi1, float* __restrict__ pd2) {
    __shared__ __align__(16) ushort Ah[128 * 32], Al[128 * 32];   // 8 KB each
    __shared__ __align__(16) ushort Bh[256 * 32];                 // 16 KB
    __shared__ float redm1[128][2], redm2[128][2];
    __shared__ int   redi1[128][2];

    const int tid = threadIdx.x;
    const int nb = blockIdx.x, mb = blockIdx.y;
    const int n0 = mb * 128, k0 = nb * 256;
    const int lane = tid & 63, w = tid >> 6;
    const int wy = w >> 1, wx = w & 1;
    const int l15 = lane & 15, lq = lane >> 4;

    size_t aoff[2]; ushort* adst_h[2]; ushort* adst_l[2];
    #pragma unroll
    for (int g = 0; g < 2; ++g) {
        int slot = (w * 2 + g) * 64 + lane;
        int t = slot >> 2, cp = slot & 3;
        int cs = cp ^ ((t >> 1) & 3);
        aoff[g] = (size_t)(n0 + t) * D_ + cs * 8;
        adst_h[g] = Ah + (w * 2 + g) * 512;
        adst_l[g] = Al + (w * 2 + g) * 512;
    }
    size_t boff[4]; ushort* bdst[4];
    #pragma unroll
    for (int g = 0; g < 4; ++g) {
        int slot = (w * 4 + g) * 64 + lane;
        int t = slot >> 2, cp = slot & 3;
        int cs = cp ^ ((t >> 1) & 3);
        boff[g] = (size_t)(k0 + t) * D_ + cs * 8;
        bdst[g] = Bh + (w * 4 + g) * 512;
    }
    int aro[4], bro[8];
    #pragma unroll
    for (int mt = 0; mt < 4; ++mt) {
        int R = wy * 64 + mt * 16 + l15;
        aro[mt] = R * 32 + ((lq ^ ((R >> 1) & 3)) * 8);
    }
    #pragma unroll
    for (int nt = 0; nt < 8; ++nt) {
        int R = wx * 128 + nt * 16 + l15;
        bro[nt] = R * 32 + ((lq ^ ((R >> 1) & 3)) * 8);
    }

    f32x4 acc[4][8];
    #pragma unroll
    for (int mt = 0; mt < 4; ++mt)
        #pragma unroll
        for (int nt = 0; nt < 8; ++nt) acc[mt][nt] = (f32x4){0.f, 0.f, 0.f, 0.f};

    for (int db = 0; db < 8; ++db) {
        const int d0 = db * 32;
        __syncthreads();
        #pragma unroll
        for (int g = 0; g < 2; ++g) {
            async_copy16(xh + aoff[g] + d0, adst_h[g]);
            async_copy16(xl + aoff[g] + d0, adst_l[g]);
        }
        #pragma unroll
        for (int g = 0; g < 4; ++g)
            async_copy16(eh + boff[g] + d0, bdst[g]);
        __syncthreads();

        bf16x8 a_h[4], a_l[4];
        #pragma unroll
        for (int mt = 0; mt < 4; ++mt) {
            a_h[mt] = *(const bf16x8*)&Ah[aro[mt]];
            a_l[mt] = *(const bf16x8*)&Al[aro[mt]];
        }
        #pragma unroll
        for (int nt = 0; nt < 8; ++nt) {
            bf16x8 b_h = *(const bf16x8*)&Bh[bro[nt]];
            #pragma unroll
            for (int mt = 0; mt < 4; ++mt) {
                acc[mt][nt] = __builtin_amdgcn_mfma_f32_16x16x32_bf16(a_h[mt], b_h, acc[mt][nt], 0, 0, 0);
                acc[mt][nt] = __builtin_amdgcn_mfma_f32_16x16x32_bf16(a_l[mt], b_h, acc[mt][nt], 0, 0, 0);
            }
        }
    }

    float cv[8];
    #pragma unroll
    for (int nt = 0; nt < 8; ++nt) cv[nt] = c[k0 + wx * 128 + nt * 16 + l15];

    float m1[16], m2[16]; int i1[16];
    #pragma unroll
    for (int mt = 0; mt < 4; ++mt)
        #pragma unroll
        for (int r = 0; r < 4; ++r) {
            int p = mt * 4 + r;
            float a = 3.4e38f, b2 = 3.4e38f; int ai = -1;
            #pragma unroll
            for (int nt = 0; nt < 8; ++nt) {
                float d = fmaf(-2.f, acc[mt][nt][r], cv[nt]);
                int k = k0 + wx * 128 + nt * 16 + l15;
                if (d < a) { b2 = a; a = d; ai = k; } else if (d < b2) b2 = d;
            }
            m1[p] = a; i1[p] = ai; m2[p] = b2;
        }
    #pragma unroll
    for (int s = 1; s < 16; s <<= 1) {
        #pragma unroll
        for (int p = 0; p < 16; ++p) {
            float n1 = __shfl_xor(m1[p], s);
            int   ni = __shfl_xor(i1[p], s);
            float n2 = __shfl_xor(m2[p], s);
            if (n1 < m1[p]) { m2[p] = fminf(m1[p], n2); m1[p] = n1; i1[p] = ni; }
            else            { m2[p] = fminf(m2[p], n1); }
        }
    }
    if (l15 == 0) {
        #pragma unroll
        for (int mt = 0; mt < 4; ++mt)
            #pragma unroll
            for (int r = 0; r < 4; ++r) {
                int p = mt * 4 + r;
                int t = wy * 64 + mt * 16 + lq * 4 + r;
                redm1[t][wx] = m1[p]; redi1[t][wx] = i1[p]; redm2[t][wx] = m2[p];
            }
    }
    __syncthreads();
    if (tid < 128) {
        float a = redm1[tid][0], b2 = redm2[tid][0]; int ai = redi1[tid][0];
        float n1 = redm1[tid][1], n2 = redm2[tid][1]; int ni = redi1[tid][1];
        if (n1 < a) { b2 = fminf(a, n2); a = n1; ai = ni; }
        else        { b2 = fminf(b2, n1); }
        size_t o = (size_t)nb * N_ + n0 + tid;
        pd1[o] = a; pi1[o] = ai; pd2[o] = b2;
    }
}

// ---------------- merge 32 blocks; enumerate pair/scan candidates -----------
// counters[0]=pairs, [1]=block-scan tasks. Coverage: true winner j in block B
// is B's top-1 (pd1<=W -> pair) or has obs >= pd2_B, forcing pd2_B<=W -> B
// gets an exact 256-code scan which covers ANY rank in B.
__global__ __launch_bounds__(256)
void merge_flag(const float* __restrict__ pd1, const int* __restrict__ pi1,
                const float* __restrict__ pd2,
                int* __restrict__ idx, int* __restrict__ counters,
                unsigned long long* __restrict__ key,
                unsigned int* __restrict__ pairs, unsigned int* __restrict__ scans) {
    int n = blockIdx.x * 256 + threadIdx.x;
    float a = 3.4e38f, b2 = 3.4e38f; int ai = -1;
    for (int nb = 0; nb < NB_; ++nb) {
        float n1 = pd1[(size_t)nb * N_ + n];
        int   ni = pi1[(size_t)nb * N_ + n];
        float n2 = pd2[(size_t)nb * N_ + n];
        if (n1 < a) { b2 = fminf(a, n2); a = n1; ai = ni; }
        else        { b2 = fminf(b2, n1); }
    }
    if (b2 - a < MARGIN) {
        const float W = a + MARGIN;
        key[n] = ~0ULL;
        idx[n] = 0x80000000 | ai;          // flagged: resolve from key later
        for (int nb = 0; nb < NB_; ++nb) {
            if (pd2[(size_t)nb * N_ + n] <= W) {
                int q = atomicAdd(&counters[1], 1);
                scans[q] = ((unsigned)n << 5) | (unsigned)nb;
            } else if (pd1[(size_t)nb * N_ + n] <= W) {
                int q = atomicAdd(&counters[0], 1);
                pairs[q] = ((unsigned)n << 13) | (unsigned)pi1[(size_t)nb * N_ + n];
            }
        }
    } else {
        idx[n] = ai;
    }
}

// ---------------- fused exact fp32 recheck (pairs + block scans) ------------
// blocks [0,128): 4 threads per (token, candidate); blocks [128,384): one
// (token, 256-code block) exact scan per task, E rows coalesced.
__global__ __launch_bounds__(256)
void recheck(const float* __restrict__ x, const float* __restrict__ E,
             const float* __restrict__ c, const unsigned int* __restrict__ pairs,
             const unsigned int* __restrict__ scans, const int* __restrict__ counters,
             unsigned long long* __restrict__ key) {
    if (blockIdx.x < 128) {
        int items = counters[0] * 4;
        for (int it = blockIdx.x * 256 + threadIdx.x; it < items; it += 128 * 256) {
            int p = it >> 2, q = it & 3;   // quads stay intact: stride % 4 == 0
            unsigned v = pairs[p];
            int n = v >> 13, k = v & 8191;
            int b = n >> 10, s = n & 1023;
            const float* xb = x + (size_t)b * 262144 + s;
            const float* eb = E + k;
            float acc = 0.f;
            const int d0 = q * 64;
            #pragma unroll 8
            for (int d = d0; d < d0 + 64; ++d)
                acc = fmaf(xb[(size_t)d * HW_], eb[(size_t)d * K_], acc);
            float o1 = __shfl_xor(acc, 1); float s2 = acc + o1;
            float o2 = __shfl_xor(s2, 2);  float tot = s2 + o2;   // ((q0+q1)+(q2+q3))
            if (q == 0) atomicMin(key + n, pack_dk(fmaf(-2.f, tot, c[k]), k));
        }
    } else {
        int cnt = counters[1];
        for (int t = blockIdx.x - 128; t < cnt; t += 256) {
            unsigned v = scans[t];
            int n = v >> 5, nb = v & 31;
            int k = nb * 256 + threadIdx.x;
            int b = n >> 10, s = n & 1023;
            const float* xb = x + (size_t)b * 262144 + s;
            float acc = 0.f;
            #pragma unroll 4
            for (int d = 0; d < D_; ++d)          // ascending d: exact ref chain
                acc = fmaf(xb[(size_t)d * HW_], E[(size_t)d * K_ + k], acc);
            float dist = fmaf(-2.f, acc, c[k]);
            atomicMin(key + n, pack_dk(dist, k));  // (dist,k) lex-min: first-min ties
        }
    }
}

// ---------------- gather + write outputs (float4, fixup via sign bit) -------
__global__ __launch_bounds__(256)
void write_kernel(const float* __restrict__ x, const float* __restrict__ E,
                  const int* __restrict__ idx, const unsigned long long* __restrict__ key,
                  float* __restrict__ out) {
    __shared__ int kst[64];
    const int n0 = blockIdx.x * 64;
    const int b = n0 >> 10, s0 = n0 & 1023;
    const int tid = threadIdx.x;
    if (tid < 64) {
        int v = idx[n0 + tid];
        int k = (v < 0) ? (int)(key[n0 + tid] & 8191ULL) : v;
        kst[tid] = k;
        out[IND_OFF + n0 + tid] = (float)k;
    }
    __syncthreads();
    const int g = tid & 15;               // float4 group of 4 tokens
    const int d0 = tid >> 4;              // 16 d-streams
    const int ka = kst[g * 4], kb2 = kst[g * 4 + 1], kc = kst[g * 4 + 2], kd = kst[g * 4 + 3];
    const float* xb = x + (size_t)b * 262144 + s0 + g * 4;
    float* o0 = out + (size_t)b * 262144 + s0 + g * 4;
    float* o1 = o0 + OUT1_OFF;
    for (int d = d0; d < D_; d += 16) {
        const float* er = E + (size_t)d * K_;
        float4 xv = *(const float4*)(xb + (size_t)d * HW_);
        float4 q;
        q.x = er[ka]; q.y = er[kb2]; q.z = er[kc]; q.w = er[kd];
        float4 r;                          // x + (q - x): replicate jnp fp32 rounding
        r.x = xv.x + (q.x - xv.x); r.y = xv.y + (q.y - xv.y);
        r.z = xv.z + (q.z - xv.z); r.w = xv.w + (q.w - xv.w);
        *(float4*)(o0 + (size_t)d * HW_) = r;
        *(float4*)(o1 + (size_t)d * HW_) = q;
    }
}

extern "C" void kernel_launch(void* const* d_in, const int* in_sizes, int n_in,
                              void* d_out, int out_size, void* d_ws, size_t ws_size,
                              hipStream_t stream) {
    const float* x = (const float*)d_in[0];
    const float* E = (const float*)d_in[1];
    float* out = (float*)d_out;

    char* p = (char*)d_ws;
    ushort* xh = (ushort*)p;                 p += (size_t)N_ * D_ * 2;   // 8 MB
    ushort* xl = (ushort*)p;                 p += (size_t)N_ * D_ * 2;   // 8 MB
    ushort* eh = (ushort*)p;                 p += (size_t)K_ * D_ * 2;   // 4 MB
    float*  c  = (float*)p;                  p += (size_t)K_ * 4;
    float*  pd1 = (float*)p;                 p += (size_t)NB_ * N_ * 4;  // 2 MB
    int*    pi1 = (int*)p;                   p += (size_t)NB_ * N_ * 4;
    float*  pd2 = (float*)p;                 p += (size_t)NB_ * N_ * 4;
    int*    idx = (int*)p;                   p += (size_t)N_ * 4;
    unsigned long long* key = (unsigned long long*)p; p += (size_t)N_ * 8;
    unsigned int* pairs = (unsigned int*)p;  p += (size_t)524288 * 4;    // 2 MB cap
    unsigned int* scans = (unsigned int*)p;  p += (size_t)524288 * 4;    // 2 MB cap
    int*    counters = (int*)p;              p += 256;

    cnorm_kernel<<<K_ / 32, 256, 0, stream>>>(E, c, counters);
    prep_x<<<dim3(32, 8, 16), 256, 0, stream>>>(x, xh, xl);
    prep_e<<<dim3(256, 8), 256, 0, stream>>>(E, eh);
    mfma_kernel<<<dim3(NB_, 128), 256, 0, stream>>>(xh, xl, eh, c, pd1, pi1, pd2);
    merge_flag<<<N_ / 256, 256, 0, stream>>>(pd1, pi1, pd2, idx, counters, key, pairs, scans);
    recheck<<<384, 256, 0, stream>>>(x, E, c, pairs, scans, counters, key);
    write_kernel<<<N_ / 64, 256, 0, stream>>>(x, E, idx, key, out);
}